// Round 1
// baseline (284.748 us; speedup 1.0000x reference)
//
#include <hip/hip_runtime.h>
#include <hip/hip_bf16.h>
#include <stdint.h>

#define NB    2048
#define NSENT 20
#define SEC   40
#define DD    100
#define UU    50
#define SP1   801

typedef __attribute__((ext_vector_type(8))) short bf16x8;
typedef __attribute__((ext_vector_type(4))) float f32x4;

__device__ __forceinline__ unsigned short f2bf(float f) {
  unsigned u = __float_as_uint(f);
  unsigned r = u + 0x7fffu + ((u >> 16) & 1u);   // round-to-nearest-even
  return (unsigned short)(r >> 16);
}

// prep: wub[b][u] = uvec[b]·wu[u] + bw[u];  whb = bf16(wh) zero-padded to [64][128]
__global__ __launch_bounds__(64) void prep_kernel(
    const float* __restrict__ inputs, const float* __restrict__ wu,
    const float* __restrict__ bw, const float* __restrict__ wh,
    float* __restrict__ wub, unsigned short* __restrict__ whb) {
  int blk = blockIdx.x, lane = threadIdx.x;
  if (blk < NB) {
    if (lane < UU) {
      const float* uv = inputs + ((size_t)blk * SP1 + (SP1 - 1)) * DD;
      const float* wr = wu + lane * DD;
      float acc = bw[lane];
      for (int d = 0; d < DD; ++d) acc = fmaf(uv[d], wr[d], acc);
      wub[blk * UU + lane] = acc;
    }
  } else {
    int t = (blk - NB) * 64 + lane;
    #pragma unroll
    for (int j = 0; j < 4; ++j) {
      int idx = t * 4 + j;
      int r = idx >> 7, c = idx & 127;
      float v = (r < UU && c < DD) ? wh[r * DD + c] : 0.f;
      whb[idx] = f2bf(v);
    }
  }
}

// one wave per (b, n): y=h·whT (MFMA), tanh, e, softmax over 40, out = alpha·h
__global__ __launch_bounds__(64, 2) void doc_kernel(
    const float* __restrict__ inputs, const float* __restrict__ vw,
    const float* __restrict__ wub, const unsigned short* __restrict__ whb,
    float* __restrict__ out) {
  __shared__ __align__(16) unsigned short hs[48 * 136];  // bf16 h tile, stride 136
  __shared__ float alpha[SEC];
  const int lane = threadIdx.x;
  const int bid = blockIdx.x;
  const int b = bid / NSENT, n = bid % NSENT;
  const float4* hsrc = (const float4*)(inputs + ((size_t)b * SP1 + (size_t)n * SEC) * DD);

  // zero K-pad region (rows 0..39, cols 96..135) so pad never makes NaN via garbage*0
  for (int i = lane; i < 200; i += 64) {
    int row = i / 5, cc = i - row * 5;
    uint4 z; z.x = z.y = z.z = z.w = 0u;
    *(uint4*)&hs[row * 136 + 96 + cc * 8] = z;
  }
  __syncthreads();

  // stage h (40x100 f32 -> bf16 LDS), 8 loads in flight per round
  #pragma unroll
  for (int half = 0; half < 2; ++half) {
    float4 stage[8];
    #pragma unroll
    for (int j = 0; j < 8; ++j) {
      int i = (half * 8 + j) * 64 + lane;
      if (i < 1000) stage[j] = hsrc[i];
    }
    #pragma unroll
    for (int j = 0; j < 8; ++j) {
      int i = (half * 8 + j) * 64 + lane;
      if (i < 1000) {
        int row = i / 25, c4 = i - row * 25;
        uint2 w;
        w.x = (unsigned)f2bf(stage[j].x) | ((unsigned)f2bf(stage[j].y) << 16);
        w.y = (unsigned)f2bf(stage[j].z) | ((unsigned)f2bf(stage[j].w) << 16);
        *(uint2*)&hs[row * 136 + c4 * 4] = w;
      }
    }
  }
  __syncthreads();

  const int col = lane & 15, grp = lane >> 4;
  f32x4 acc[3][4];
  #pragma unroll
  for (int mt = 0; mt < 3; ++mt)
    #pragma unroll
    for (int nt = 0; nt < 4; ++nt) {
      f32x4 z = {0.f, 0.f, 0.f, 0.f};
      acc[mt][nt] = z;
    }

  #pragma unroll
  for (int kt = 0; kt < 4; ++kt) {
    bf16x8 bfrag[4];
    #pragma unroll
    for (int nt = 0; nt < 4; ++nt)
      bfrag[nt] = *(const bf16x8*)(whb + ((nt * 16 + col) << 7) + kt * 32 + grp * 8);
    #pragma unroll
    for (int mt = 0; mt < 3; ++mt) {
      bf16x8 af = *(const bf16x8*)&hs[(mt * 16 + col) * 136 + kt * 32 + grp * 8];
      #pragma unroll
      for (int nt = 0; nt < 4; ++nt)
        acc[mt][nt] = __builtin_amdgcn_mfma_f32_16x16x32_bf16(af, bfrag[nt], acc[mt][nt], 0, 0, 0);
    }
  }

  // epilogue: e[row] = sum_u tanh(y + wub[u]) * vw[u]
  float vwv[4], wubv[4];
  #pragma unroll
  for (int nt = 0; nt < 4; ++nt) {
    int u = nt * 16 + col;
    bool val = (u < UU);
    vwv[nt] = val ? vw[u] : 0.f;
    wubv[nt] = val ? wub[b * UU + u] : 0.f;
  }
  float el[3][4];
  #pragma unroll
  for (int mt = 0; mt < 3; ++mt) {
    #pragma unroll
    for (int r = 0; r < 4; ++r) {
      float s = 0.f;
      #pragma unroll
      for (int nt = 0; nt < 4; ++nt) {
        float x = acc[mt][nt][r] + wubv[nt];
        x = fminf(fmaxf(x, -15.f), 15.f);
        float E = __expf(2.f * x);
        float t = 1.f - 2.f / (E + 1.f);
        s = fmaf(t, vwv[nt], s);
      }
      // reduce over the 16 lanes of this group (cols of this row)
      s += __shfl_xor(s, 1);
      s += __shfl_xor(s, 2);
      s += __shfl_xor(s, 4);
      s += __shfl_xor(s, 8);
      el[mt][r] = s;
    }
  }
  // softmax over rows < 40 (lane holds rows mt*16 + grp*4 + r)
  float mx = -1e30f;
  #pragma unroll
  for (int mt = 0; mt < 3; ++mt)
    #pragma unroll
    for (int r = 0; r < 4; ++r) {
      int row = mt * 16 + grp * 4 + r;
      if (row < SEC) mx = fmaxf(mx, el[mt][r]);
    }
  mx = fmaxf(mx, __shfl_xor(mx, 16));
  mx = fmaxf(mx, __shfl_xor(mx, 32));
  float p[3][4];
  float sum = 0.f;
  #pragma unroll
  for (int mt = 0; mt < 3; ++mt)
    #pragma unroll
    for (int r = 0; r < 4; ++r) {
      int row = mt * 16 + grp * 4 + r;
      float pe = (row < SEC) ? __expf(el[mt][r] - mx) : 0.f;
      p[mt][r] = pe;
      sum += pe;
    }
  sum += __shfl_xor(sum, 16);
  sum += __shfl_xor(sum, 32);
  float rinv = 1.f / sum;
  if (col == 0) {
    #pragma unroll
    for (int mt = 0; mt < 3; ++mt)
      #pragma unroll
      for (int r = 0; r < 4; ++r) {
        int row = mt * 16 + grp * 4 + r;
        if (row < SEC) alpha[row] = p[mt][r] * rinv;
      }
  }
  __syncthreads();

  // out[b][n][d] = sum_s alpha[s] * h[s][d]; lane handles d = 2*lane, 2*lane+1
  if (lane < DD / 2) {
    float f0 = 0.f, f1 = 0.f;
    #pragma unroll 8
    for (int s = 0; s < SEC; ++s) {
      float a = alpha[s];
      unsigned w = *(const unsigned*)&hs[s * 136 + lane * 2];
      f0 = fmaf(a, __uint_as_float(w << 16), f0);
      f1 = fmaf(a, __uint_as_float(w & 0xffff0000u), f1);
    }
    float2 o; o.x = f0; o.y = f1;
    *(float2*)(out + ((size_t)b * NSENT + n) * DD + lane * 2) = o;
  }
}

extern "C" void kernel_launch(void* const* d_in, const int* in_sizes, int n_in,
                              void* d_out, int out_size, void* d_ws, size_t ws_size,
                              hipStream_t stream) {
  const float* inputs = (const float*)d_in[0];
  const float* vw     = (const float*)d_in[1];
  const float* wh     = (const float*)d_in[2];
  const float* wu     = (const float*)d_in[3];
  const float* bw     = (const float*)d_in[4];
  float* out = (float*)d_out;

  unsigned short* whb = (unsigned short*)d_ws;             // 64*128*2 = 16384 B
  float* wub = (float*)((char*)d_ws + 16384);              // 2048*50*4 = 409600 B

  prep_kernel<<<NB + 32, 64, 0, stream>>>(inputs, wu, bw, wh, wub, whb);
  doc_kernel<<<NB * NSENT, 64, 0, stream>>>(inputs, vw, wub, whb, out);
}

// Round 2
// 177.156 us; speedup vs baseline: 1.6073x; 1.6073x over previous
//
#include <hip/hip_runtime.h>
#include <hip/hip_bf16.h>
#include <stdint.h>

#define NB    2048
#define NSENT 20
#define SEC   40
#define DD    100
#define UU    50
#define SP1   801

typedef __attribute__((ext_vector_type(8))) short bf16x8;
typedef __attribute__((ext_vector_type(4))) float f32x4;

__device__ __forceinline__ unsigned short f2bf(float f) {
  unsigned u = __float_as_uint(f);
  unsigned r = u + 0x7fffu + ((u >> 16) & 1u);   // round-to-nearest-even
  return (unsigned short)(r >> 16);
}

// One persistent wave per document b. Pipeline over its 20 sentences:
// issue loads(t+1) -> compute tile t (MFMA y=h*whT, tanh, e, softmax, alpha*h).
__global__ __launch_bounds__(64, 2) void doc_kernel(
    const float* __restrict__ inputs, const float* __restrict__ vw,
    const float* __restrict__ wh, const float* __restrict__ wu,
    const float* __restrict__ bw, float* __restrict__ out) {
  __shared__ __align__(16) unsigned short hs[48 * 136];  // bf16 h tile, stride 136
  __shared__ float alpha[SEC];
  const int lane = threadIdx.x;
  const int b = blockIdx.x;
  const int col = lane & 15, grp = lane >> 4;

  const float4* base4 = (const float4*)(inputs + (size_t)b * SP1 * DD);

  // ---- issue tile-0 loads immediately (cover prologue latency) ----
  float4 stage[16];
  #pragma unroll
  for (int j = 0; j < 15; ++j) stage[j] = base4[j * 64 + lane];
  if (lane < 40) stage[15] = base4[960 + lane];

  // ---- zero K-pad cols [100,136) of rows 0..39; persists across all tiles ----
  for (int i = lane; i < 360; i += 64) {
    int row = i / 9, c = i - row * 9;
    uint2 z; z.x = 0u; z.y = 0u;
    *(uint2*)&hs[row * 136 + 100 + c * 4] = z;
  }

  // ---- B fragments: bf16(wh), zero-padded, resident in VGPRs ----
  bf16x8 bfrag[4][4];
  #pragma unroll
  for (int nt = 0; nt < 4; ++nt) {
    int u = nt * 16 + col;
    #pragma unroll
    for (int kt = 0; kt < 4; ++kt) {
      bf16x8 f;
      #pragma unroll
      for (int j = 0; j < 8; ++j) {
        int k = kt * 32 + grp * 8 + j;
        float v = (u < UU && k < DD) ? wh[u * DD + k] : 0.f;
        f[j] = (short)f2bf(v);
      }
      bfrag[nt][kt] = f;
    }
  }

  // ---- wub[u=lane] = uvec[b]·wu[u] + bw[u] (fused prep) ----
  float wubacc;
  {
    int ur = lane < UU ? lane : UU - 1;
    const float4* uv4 = (const float4*)(inputs + ((size_t)b * SP1 + SP1 - 1) * DD);
    const float4* wr4 = (const float4*)(wu + ur * DD);
    float a0 = bw[ur];
    #pragma unroll 5
    for (int q = 0; q < 25; ++q) {
      float4 uq = uv4[q], wq = wr4[q];
      a0 = fmaf(uq.x, wq.x, a0); a0 = fmaf(uq.y, wq.y, a0);
      a0 = fmaf(uq.z, wq.z, a0); a0 = fmaf(uq.w, wq.w, a0);
    }
    wubacc = a0;
  }
  float vwv[4], wubv[4];
  #pragma unroll
  for (int nt = 0; nt < 4; ++nt) {
    int u = nt * 16 + col;
    float wv = __shfl(wubacc, nt * 16 + col);
    vwv[nt] = (u < UU) ? vw[u] : 0.f;
    wubv[nt] = (u < UU) ? wv : 0.f;
  }

  float* outb = out + (size_t)b * NSENT * DD;

  #pragma unroll 1
  for (int t = 0; t < NSENT; ++t) {
    // ---- convert tile t (in regs) -> bf16 LDS ----
    #pragma unroll
    for (int j = 0; j < 16; ++j) {
      if (j < 15 || lane < 40) {
        int idx = j * 64 + lane;
        int row = idx / 25, c4 = idx - row * 25;
        uint2 w;
        w.x = (unsigned)f2bf(stage[j].x) | ((unsigned)f2bf(stage[j].y) << 16);
        w.y = (unsigned)f2bf(stage[j].z) | ((unsigned)f2bf(stage[j].w) << 16);
        *(uint2*)&hs[row * 136 + c4 * 4] = w;
      }
    }

    // ---- issue tile t+1 loads (overlap with compute below) ----
    if (t + 1 < NSENT) {
      const float4* nb4 = base4 + (size_t)(t + 1) * 1000;
      #pragma unroll
      for (int j = 0; j < 15; ++j) stage[j] = nb4[j * 64 + lane];
      if (lane < 40) stage[15] = nb4[960 + lane];
    }

    // ---- MFMA: y = h · wh^T ----
    f32x4 acc[3][4];
    #pragma unroll
    for (int mt = 0; mt < 3; ++mt)
      #pragma unroll
      for (int nt = 0; nt < 4; ++nt) {
        f32x4 z = {0.f, 0.f, 0.f, 0.f};
        acc[mt][nt] = z;
      }
    #pragma unroll
    for (int kt = 0; kt < 4; ++kt) {
      #pragma unroll
      for (int mt = 0; mt < 3; ++mt) {
        bf16x8 af = *(const bf16x8*)&hs[(mt * 16 + col) * 136 + kt * 32 + grp * 8];
        #pragma unroll
        for (int nt = 0; nt < 4; ++nt)
          acc[mt][nt] = __builtin_amdgcn_mfma_f32_16x16x32_bf16(af, bfrag[nt][kt], acc[mt][nt], 0, 0, 0);
      }
    }

    // ---- e[row] = sum_u tanh(y + wub[u]) * vw[u] ----
    float el[3][4];
    #pragma unroll
    for (int mt = 0; mt < 3; ++mt) {
      #pragma unroll
      for (int r = 0; r < 4; ++r) {
        float s = 0.f;
        #pragma unroll
        for (int nt = 0; nt < 4; ++nt) {
          float x = acc[mt][nt][r] + wubv[nt];
          x = fminf(fmaxf(x, -15.f), 15.f);
          float E = __expf(2.f * x);
          float tt = 1.f - 2.f / (E + 1.f);
          s = fmaf(tt, vwv[nt], s);
        }
        s += __shfl_xor(s, 1);
        s += __shfl_xor(s, 2);
        s += __shfl_xor(s, 4);
        s += __shfl_xor(s, 8);
        el[mt][r] = s;
      }
    }

    // ---- softmax over 40 rows (lane holds rows mt*16 + grp*4 + r) ----
    float mx = -1e30f;
    #pragma unroll
    for (int mt = 0; mt < 3; ++mt)
      #pragma unroll
      for (int r = 0; r < 4; ++r) {
        int row = mt * 16 + grp * 4 + r;
        if (row < SEC) mx = fmaxf(mx, el[mt][r]);
      }
    mx = fmaxf(mx, __shfl_xor(mx, 16));
    mx = fmaxf(mx, __shfl_xor(mx, 32));
    float p[3][4];
    float sum = 0.f;
    #pragma unroll
    for (int mt = 0; mt < 3; ++mt)
      #pragma unroll
      for (int r = 0; r < 4; ++r) {
        int row = mt * 16 + grp * 4 + r;
        float pe = (row < SEC) ? __expf(el[mt][r] - mx) : 0.f;
        p[mt][r] = pe;
        sum += pe;
      }
    sum += __shfl_xor(sum, 16);
    sum += __shfl_xor(sum, 32);
    float rinv = 1.f / sum;
    if (col == 0) {
      #pragma unroll
      for (int mt = 0; mt < 3; ++mt)
        #pragma unroll
        for (int r = 0; r < 4; ++r) {
          int row = mt * 16 + grp * 4 + r;
          if (row < SEC) alpha[row] = p[mt][r] * rinv;
        }
    }

    // ---- out[b][t][d] = sum_s alpha[s] * h[s][d] ----
    if (lane < DD / 2) {
      float f0 = 0.f, f1 = 0.f;
      #pragma unroll 8
      for (int s = 0; s < SEC; ++s) {
        float a = alpha[s];
        unsigned w = *(const unsigned*)&hs[s * 136 + lane * 2];
        f0 = fmaf(a, __uint_as_float(w << 16), f0);
        f1 = fmaf(a, __uint_as_float(w & 0xffff0000u), f1);
      }
      float2 o; o.x = f0; o.y = f1;
      *(float2*)(outb + t * DD + lane * 2) = o;
    }
  }
}

extern "C" void kernel_launch(void* const* d_in, const int* in_sizes, int n_in,
                              void* d_out, int out_size, void* d_ws, size_t ws_size,
                              hipStream_t stream) {
  const float* inputs = (const float*)d_in[0];
  const float* vw     = (const float*)d_in[1];
  const float* wh     = (const float*)d_in[2];
  const float* wu     = (const float*)d_in[3];
  const float* bw     = (const float*)d_in[4];
  float* out = (float*)d_out;

  doc_kernel<<<NB, 64, 0, stream>>>(inputs, vw, wh, wu, bw, out);
}

// Round 3
// 165.371 us; speedup vs baseline: 1.7219x; 1.0713x over previous
//
#include <hip/hip_runtime.h>
#include <hip/hip_bf16.h>
#include <stdint.h>

#define NB    2048
#define NSENT 20
#define SEC   40
#define DD    100
#define UU    50
#define SP1   801
#define STRIDE 136   // shorts; multiple of 8 (b128 align), 2-way banks only

typedef __attribute__((ext_vector_type(8))) short bf16x8;
typedef __attribute__((ext_vector_type(4))) float f32x4;

__device__ __forceinline__ unsigned f2bf(float f) {
  unsigned u = __float_as_uint(f);
  unsigned r = u + 0x7fffu + ((u >> 16) & 1u);   // round-to-nearest-even
  return r >> 16;
}

// One 4-wave block per document b. Waves cooperate on each sentence tile:
// wave w owns u-tile w of C[u][s] = (wh . h^T); e/softmax/out exchanged via LDS.
__global__ __launch_bounds__(256, 4) void doc_kernel(
    const float* __restrict__ inputs, const float* __restrict__ vw,
    const float* __restrict__ wh, const float* __restrict__ wu,
    const float* __restrict__ bw, float* __restrict__ out) {
  __shared__ __align__(16) unsigned short hs[2][48 * STRIDE]; // bf16 h tiles (dbuf)
  __shared__ __align__(16) float epart[3 * 16 * 4];           // [st][col][w]
  __shared__ float alphas[SEC];
  __shared__ __align__(16) float2 opart[50 * 4];              // [dpair][w]

  const int tid  = threadIdx.x;
  const int w    = tid >> 6, lane = tid & 63;
  const int col  = lane & 15, grp = lane >> 4;
  const int b    = blockIdx.x;

  const float4* base4 = (const float4*)(inputs + (size_t)b * SP1 * DD);

  // ---- issue tile-0 loads immediately ----
  float4 stage[4];
  #pragma unroll
  for (int j = 0; j < 4; ++j) {
    int idx = j * 256 + tid;
    if (idx < 1000) stage[j] = base4[idx];
  }

  // ---- zero both h buffers once (K-pad cols + rows 40..47 stay zero) ----
  {
    uint4 z; z.x = z.y = z.z = z.w = 0u;
    uint4* p = (uint4*)&hs[0][0];
    #pragma unroll 1
    for (int i = tid; i < 2 * 48 * STRIDE / 8; i += 256) p[i] = z;
  }

  // ---- A fragments: this wave's 16 wh rows (u = 16w + col), resident ----
  bf16x8 afrag[4];
  {
    int u = w * 16 + col;
    #pragma unroll
    for (int kt = 0; kt < 4; ++kt) {
      bf16x8 f;
      #pragma unroll
      for (int j = 0; j < 8; ++j) {
        int k = kt * 32 + grp * 8 + j;
        float v = (u < UU && k < DD) ? wh[u * DD + k] : 0.f;
        f[j] = (short)f2bf(v);
      }
      afrag[kt] = f;
    }
  }

  // ---- wub[u=lane] = uvec[b]·wu[u] + bw[u] (each wave redundantly) ----
  float wubacc;
  {
    int ur = lane < UU ? lane : UU - 1;
    const float4* uv4 = (const float4*)(inputs + ((size_t)b * SP1 + SP1 - 1) * DD);
    const float4* wr4 = (const float4*)(wu + ur * DD);
    float a0 = bw[ur];
    #pragma unroll 5
    for (int q = 0; q < 25; ++q) {
      float4 uq = uv4[q], wq = wr4[q];
      a0 = fmaf(uq.x, wq.x, a0); a0 = fmaf(uq.y, wq.y, a0);
      a0 = fmaf(uq.z, wq.z, a0); a0 = fmaf(uq.w, wq.w, a0);
    }
    wubacc = a0;
  }
  float vwr[4], wubr[4];
  #pragma unroll
  for (int r = 0; r < 4; ++r) {
    int u = w * 16 + grp * 4 + r;
    float wv = __shfl(wubacc, u & 63);
    bool val = (u < UU);
    vwr[r]  = val ? vw[u] : 0.f;
    wubr[r] = val ? wv : 0.f;
  }

  __syncthreads();   // B0: zero-fill visible

  float* outb = out + (size_t)b * NSENT * DD;
  int cur = 0;

  #pragma unroll 1
  for (int t = 0; t < NSENT; ++t) {
    // ---- convert tile t (stage regs, f32) -> bf16 LDS (cooperative) ----
    #pragma unroll
    for (int j = 0; j < 4; ++j) {
      int idx = j * 256 + tid;
      if (idx < 1000) {
        int row = idx / 25, c4 = idx - row * 25;
        uint2 wv;
        wv.x = f2bf(stage[j].x) | (f2bf(stage[j].y) << 16);
        wv.y = f2bf(stage[j].z) | (f2bf(stage[j].w) << 16);
        *(uint2*)&hs[cur][row * STRIDE + c4 * 4] = wv;
      }
    }
    __syncthreads();   // B1

    // ---- issue tile t+1 loads; pin them before the compute phase ----
    if (t + 1 < NSENT) {
      const float4* nb4 = base4 + (size_t)(t + 1) * 1000;
      #pragma unroll
      for (int j = 0; j < 4; ++j) {
        int idx = j * 256 + tid;
        if (idx < 1000) stage[j] = nb4[idx];
      }
    }
    __builtin_amdgcn_sched_barrier(0);

    // ---- MFMA (swapped): acc[st] = C[u-tile w][s-tile st] ----
    f32x4 acc[3];
    #pragma unroll
    for (int st = 0; st < 3; ++st) { f32x4 z = {0.f,0.f,0.f,0.f}; acc[st] = z; }
    #pragma unroll
    for (int kt = 0; kt < 4; ++kt) {
      #pragma unroll
      for (int st = 0; st < 3; ++st) {
        bf16x8 hf = *(const bf16x8*)&hs[cur][(st * 16 + col) * STRIDE + kt * 32 + grp * 8];
        acc[st] = __builtin_amdgcn_mfma_f32_16x16x32_bf16(afrag[kt], hf, acc[st], 0, 0, 0);
      }
    }

    // ---- partial e[s]: sum over this wave's u = 16w+grp*4+r ----
    #pragma unroll
    for (int st = 0; st < 3; ++st) {
      float s = 0.f;
      #pragma unroll
      for (int r = 0; r < 4; ++r) {
        float x = acc[st][r] + wubr[r];
        x = fminf(fmaxf(x, -15.f), 15.f);
        float E = __expf(2.f * x);
        float tt = 1.f - 2.f * __builtin_amdgcn_rcpf(E + 1.f);
        s = fmaf(tt, vwr[r], s);
      }
      s += __shfl_xor(s, 16);
      s += __shfl_xor(s, 32);
      if (grp == 0) epart[st * 64 + col * 4 + w] = s;
    }
    __syncthreads();   // B2

    // ---- full e, softmax over s<40 (redundant per wave; lane holds s=st*16+col) ----
    f32x4 q0 = *(const f32x4*)&epart[0 * 64 + col * 4];
    f32x4 q1 = *(const f32x4*)&epart[1 * 64 + col * 4];
    f32x4 q2 = *(const f32x4*)&epart[2 * 64 + col * 4];
    float e0 = (q0[0] + q0[1]) + (q0[2] + q0[3]);
    float e1 = (q1[0] + q1[1]) + (q1[2] + q1[3]);
    float e2 = (q2[0] + q2[1]) + (q2[2] + q2[3]);
    float mx = fmaxf(e0, e1);
    if (col < 8) mx = fmaxf(mx, e2);
    mx = fmaxf(mx, __shfl_xor(mx, 1));
    mx = fmaxf(mx, __shfl_xor(mx, 2));
    mx = fmaxf(mx, __shfl_xor(mx, 4));
    mx = fmaxf(mx, __shfl_xor(mx, 8));
    float p0 = __expf(e0 - mx);
    float p1 = __expf(e1 - mx);
    float p2 = (col < 8) ? __expf(e2 - mx) : 0.f;
    float sum = p0 + p1 + p2;
    sum += __shfl_xor(sum, 1);
    sum += __shfl_xor(sum, 2);
    sum += __shfl_xor(sum, 4);
    sum += __shfl_xor(sum, 8);
    float rinv = __builtin_amdgcn_rcpf(sum);
    if (w == 0 && grp == 0) {
      alphas[col]      = p0 * rinv;
      alphas[16 + col] = p1 * rinv;
      if (col < 8) alphas[32 + col] = p2 * rinv;
    }
    __syncthreads();   // B3

    // ---- out partial: wave w sums s in [10w,10w+10), lane = d-pair ----
    if (lane < 50) {
      float f0 = 0.f, f1 = 0.f;
      #pragma unroll
      for (int i = 0; i < 10; ++i) {
        int s = w * 10 + i;
        float a = alphas[s];
        unsigned hh = *(const unsigned*)&hs[cur][s * STRIDE + lane * 2];
        f0 = fmaf(a, __uint_as_float(hh << 16), f0);
        f1 = fmaf(a, __uint_as_float(hh & 0xffff0000u), f1);
      }
      float2 o; o.x = f0; o.y = f1;
      opart[lane * 4 + w] = o;
    }
    __syncthreads();   // B4

    if (w == 0 && lane < 50) {
      f32x4 a0 = *(const f32x4*)&opart[lane * 4];      // w0,w1 partials
      f32x4 a1 = *(const f32x4*)&opart[lane * 4 + 2];  // w2,w3 partials
      float2 o;
      o.x = (a0[0] + a0[2]) + (a1[0] + a1[2]);
      o.y = (a0[1] + a0[3]) + (a1[1] + a1[3]);
      *(float2*)(outb + t * DD + lane * 2) = o;
    }
    cur ^= 1;
  }
}

extern "C" void kernel_launch(void* const* d_in, const int* in_sizes, int n_in,
                              void* d_out, int out_size, void* d_ws, size_t ws_size,
                              hipStream_t stream) {
  const float* inputs = (const float*)d_in[0];
  const float* vw     = (const float*)d_in[1];
  const float* wh     = (const float*)d_in[2];
  const float* wu     = (const float*)d_in[3];
  const float* bw     = (const float*)d_in[4];
  float* out = (float*)d_out;

  doc_kernel<<<NB, 256, 0, stream>>>(inputs, vw, wh, wu, bw, out);
}